// Round 6
// baseline (1081.610 us; speedup 1.0000x reference)
//
#include <hip/hip_runtime.h>

#define T_STEPS 2000
#define NBATCH  256
#define HID     51
#define FEAT    49
#define ROWF4   784                         // float4 per 64-step chunk (64*49/4)
#define XTOT4   (NBATCH * T_STEPS * FEAT / 4)
#define XBUFB   13312                       // 13 * 1024 B staged per chunk (>= 12544)

typedef _Float16 v2h __attribute__((ext_vector_type(2)));

__device__ __forceinline__ float rl(float v, int lane) {
    return __int_as_float(__builtin_amdgcn_readlane(__float_as_int(v), lane));
}
__device__ __forceinline__ int rli(int v, int lane) {
    return __builtin_amdgcn_readlane(v, lane);
}
__device__ __forceinline__ float sigmoidf_fast(float x) {
    return __builtin_amdgcn_rcpf(1.0f + __builtin_amdgcn_exp2f(-1.4426950408889634f * x));
}
__device__ __forceinline__ float tanhf_fast(float x) {
    return 1.0f - 2.0f * __builtin_amdgcn_rcpf(1.0f + __builtin_amdgcn_exp2f(2.8853900817779268f * x));
}
__device__ __forceinline__ int packh2(float lo, float hi) {
    v2h p = (v2h){(_Float16)lo, (_Float16)hi};
    return __builtin_bit_cast(int, p);
}
// packed f16 FMA: full-rate (2cy) vs v_dot2_f32_f16's measured half-rate (4cy).
__device__ __forceinline__ v2h pkfma(int w, int s, v2h acc) {
    return __builtin_elementwise_fma(__builtin_bit_cast(v2h, w),
                                     __builtin_bit_cast(v2h, s), acc);
}
// collapse packed-f16 accumulator into f32: one fdot2 against (1,1), exact.
__device__ __forceinline__ float pksum(v2h p, float base) {
    return __builtin_amdgcn_fdot2(p, (v2h){(_Float16)1.0f, (_Float16)1.0f},
                                  base, false);
}
// async global->LDS, 16B per lane: LDS dest = wave-uniform base + lane*16,
// global src = per-lane address. Tracked by vmcnt.
__device__ __forceinline__ void gl_lds16(const void* g, void* l) {
    __builtin_amdgcn_global_load_lds(
        (const __attribute__((address_space(1))) unsigned int*)g,
        (__attribute__((address_space(3))) unsigned int*)l, 16, 0, 0);
}
__device__ __forceinline__ float row_dot(const float* row, const float* __restrict__ Wl) {
    float a0 = 0, a1 = 0, a2 = 0, a3 = 0, a4 = 0, a5 = 0, a6 = 0;
#pragma unroll
    for (int j = 0; j < FEAT; j += 7) {
        a0 = fmaf(row[j    ], Wl[j    ], a0);
        a1 = fmaf(row[j + 1], Wl[j + 1], a1);
        a2 = fmaf(row[j + 2], Wl[j + 2], a2);
        a3 = fmaf(row[j + 3], Wl[j + 3], a3);
        a4 = fmaf(row[j + 4], Wl[j + 4], a4);
        a5 = fmaf(row[j + 5], Wl[j + 5], a5);
        a6 = fmaf(row[j + 6], Wl[j + 6], a6);
    }
    return ((a0 + a1) + (a2 + a3)) + ((a4 + a5) + a6);
}

#define REP26(F) F(0) F(1) F(2) F(3) F(4) F(5) F(6) F(7) F(8) F(9) F(10) F(11) F(12) \
                 F(13) F(14) F(15) F(16) F(17) F(18) F(19) F(20) F(21) F(22) F(23) F(24) F(25)

// SINGLE wave per sample, lane l (<51) owns hidden unit l (all 4 gates);
// lane 51 owns LSTM2 (Whh2 folded into pair-25-hi). Zero barriers.
// Round-6 change: gate preacts accumulate via v_pk_fma_f16 (full-rate, 2cy)
// in two packed-f16 chains of 13 per gate, collapsed to f32 by ONE fdot2
// against (1,1) each. Rounds 0-vs-5 issue-cycle fit shows v_dot2_f32_f16
// issues at ~4cy/instr on wave64: the 104-dot2 block was ~416 of the ~770
// measured issue cycles/step. New dot block: 104 pk_fma (208) + 8 dot2 (32).
__global__ __attribute__((amdgpu_flat_work_group_size(64, 64), amdgpu_waves_per_eu(1, 1)))
void rnn_kernel(
    const float* __restrict__ x,
    const float* __restrict__ Wl, const float* __restrict__ bl,
    const float* __restrict__ Wih1, const float* __restrict__ Whh1,
    const float* __restrict__ bih1, const float* __restrict__ bhh1,
    const float* __restrict__ Wih2, const float* __restrict__ Whh2,
    const float* __restrict__ bih2, const float* __restrict__ bhh2,
    const float* __restrict__ Wa, const float* __restrict__ ba,
    float* __restrict__ out)
{
    const int n    = blockIdx.x;
    const int lane = threadIdx.x;          // 0..63
    float* optr = out + (size_t)n * T_STEPS;
    const float4* x4 = (const float4*)x;
    const int sbase = n * (T_STEPS * FEAT / 4);

    __shared__ __align__(16) char xls[2 * XBUFB];   // double-buffered x-tile
    __shared__ float ob[64];                        // output ring (lane 51 writes)

    // ---- weights: 4 gates x 26 packed f16 pairs per lane ----
#define DECLW(j) int w0_##j, w1_##j, w2_##j, w3_##j; int sh_##j;
    REP26(DECLW)

    const float msk = (lane <= HID) ? 1.0f : 0.0f;   // lanes 52..63 masked to 0
    const float m51 = (lane == HID) ? 1.0f : 0.0f;
#define LOADW(j, wv) { float lo = srow[2*(j)] * msk; \
        float hi = (2*(j)+1 < HID) ? srow[2*(j)+1] * msk : wh2; \
        wv##_##j = packh2(lo, hi); asm("" : "+v"(wv##_##j)); }
#define LOADW0(j) LOADW(j, w0)
#define LOADW1(j) LOADW(j, w1)
#define LOADW2(j) LOADW(j, w2)
#define LOADW3(j) LOADW(j, w3)
    { const float* srow = (lane < HID) ? (Whh1 + (0 * HID + lane) * HID) : (Wih2 + 0 * HID);
      const float wh2 = Whh2[0] * m51;  REP26(LOADW0) }
    { const float* srow = (lane < HID) ? (Whh1 + (1 * HID + lane) * HID) : (Wih2 + 1 * HID);
      const float wh2 = Whh2[1] * m51;  REP26(LOADW1) }
    { const float* srow = (lane < HID) ? (Whh1 + (2 * HID + lane) * HID) : (Wih2 + 2 * HID);
      const float wh2 = Whh2[2] * m51;  REP26(LOADW2) }
    { const float* srow = (lane < HID) ? (Whh1 + (3 * HID + lane) * HID) : (Wih2 + 3 * HID);
      const float wh2 = Whh2[3] * m51;  REP26(LOADW3) }

    float wx0 = 0, wx1 = 0, wx2 = 0, wx3 = 0;
    float b0 = 0, b1 = 0, b2 = 0, b3 = 0;
    if (lane < HID) {
        wx0 = Wih1[0 * HID + lane]; b0 = bih1[0 * HID + lane] + bhh1[0 * HID + lane];
        wx1 = Wih1[1 * HID + lane]; b1 = bih1[1 * HID + lane] + bhh1[1 * HID + lane];
        wx2 = Wih1[2 * HID + lane]; b2 = bih1[2 * HID + lane] + bhh1[2 * HID + lane];
        wx3 = Wih1[3 * HID + lane]; b3 = bih1[3 * HID + lane] + bhh1[3 * HID + lane];
    } else if (lane == HID) {
        b0 = bih2[0] + bhh2[0]; b1 = bih2[1] + bhh2[1];
        b2 = bih2[2] + bhh2[2]; b3 = bih2[3] + bhh2[3];
    }
    const float wav = Wa[0], bav = ba[0];
    const float bl0 = bl[0];

#define INITS(j) sh_##j = 0;
    REP26(INITS)

    float c = 0.0f, h = 0.0f;

    // ---- x staging: 13 x global_load_lds(16B) per 64-step chunk, 0 VGPRs ----
#define STAGE(cbase, buf) { \
    _Pragma("unroll") \
    for (int i_ = 0; i_ < 13; ++i_) { \
        int g_ = (cbase) + i_ * 64 + lane; g_ = g_ < XTOT4 ? g_ : (XTOT4 - 1); \
        gl_lds16(x4 + g_, xls + (buf) * XBUFB + i_ * 1024); \
    } }
#define VMWAIT asm volatile("s_waitcnt vmcnt(0)" ::: "memory");
#define ROWDOT(dst, buf) { \
    const float* row_ = (const float*)(xls + (buf) * XBUFB) + lane * FEAT; \
    float d_ = row_dot(row_, Wl); dst = fmaxf(d_ + bl0, 0.0f); }

    float xa, xb;
    STAGE(sbase, 0)                       // chunk 0 -> buf0
    STAGE(sbase + ROWF4, 1)               // chunk 1 -> buf1
    VMWAIT
    ROWDOT(xa, 0)
    ROWDOT(xb, 1)
    STAGE(sbase + 2 * ROWF4, 0)           // chunk 2 -> buf0 (chunk 0 consumed)

#pragma unroll 1
    for (int t = 0; t <= T_STEPS; ++t) {
        if ((t & 63) == 0 && t > 0 && t < T_STEPS) {
            const int k = t >> 6;
            xa = xb;
            VMWAIT                                   // chunk k+1 stage complete
            ROWDOT(xb, (k + 1) & 1)                  // precompute chunk k+1
            STAGE(sbase + (k + 2) * ROWF4, k & 1)    // chunk k+2 in flight
        }
        const float xt = rl(xa, t & 63);

        // ---- 4 gate preacts: 8 packed-f16 FMA chains (even/odd j split) ----
        const v2h z2 = (v2h){(_Float16)0.0f, (_Float16)0.0f};
        v2h p0A = z2, p0B = z2, p1A = z2, p1B = z2;
        v2h p2A = z2, p2B = z2, p3A = z2, p3B = z2;
#define DOT(j) { if ((j) & 1) { p0B = pkfma(w0_##j, sh_##j, p0B); p1B = pkfma(w1_##j, sh_##j, p1B); \
                                p2B = pkfma(w2_##j, sh_##j, p2B); p3B = pkfma(w3_##j, sh_##j, p3B); } \
                 else         { p0A = pkfma(w0_##j, sh_##j, p0A); p1A = pkfma(w1_##j, sh_##j, p1A); \
                                p2A = pkfma(w2_##j, sh_##j, p2A); p3A = pkfma(w3_##j, sh_##j, p3A); } }
        REP26(DOT)

        // ---- collapse packed accums to f32 (2 fdot2 per gate, exact) ----
        const float a0 = pksum(p0B, pksum(p0A, fmaf(wx0, xt, b0)));
        const float a1 = pksum(p1B, pksum(p1A, fmaf(wx1, xt, b1)));
        const float a2 = pksum(p2B, pksum(p2A, fmaf(wx2, xt, b2)));
        const float a3 = pksum(p3B, pksum(p3A, fmaf(wx3, xt, b3)));

        // ---- lane-local activations + state update (no exchange needed) ----
        const float gi = sigmoidf_fast(a0);
        const float gf = sigmoidf_fast(a1);
        const float gg = tanhf_fast(a2);
        const float go = sigmoidf_fast(a3);

        c = fmaf(gf, c, gi * gg);
        h = go * tanhf_fast(c);
        if (t == 0 && lane >= HID) { c = 0.0f; h = 0.0f; }   // LSTM2 zero init (skew)

        // ---- output: lane 51's h2 -> ob slot (t-1)&63 (exec-masked ds_write) ----
        if (lane == HID && t > 0) ob[(t - 1) & 63] = fmaf(h, wav, bav);

        // ---- h broadcast: f16 cvt + dpp neighbor + 26 readlanes ----
        int hz = (int)(unsigned)__builtin_bit_cast(unsigned short, (_Float16)h);
        int nb = __builtin_amdgcn_mov_dpp(hz, 0xB1, 0xF, 0xF, true);  // lane r <-> r^1
        int pair = hz | (nb << 16);
#define BCAST(j) sh_##j = rli(pair, 2 * (j));
        REP26(BCAST)

        // coalesced flush of the previous 64 outputs (slot 63 just written)
        if ((t & 63) == 0 && t > 0) optr[t - 64 + lane] = ob[lane];
    }

    // final partial flush: outs 1984..1999 live in slots 0..15
    if (lane < 16) optr[1984 + lane] = ob[lane];
}

extern "C" void kernel_launch(void* const* d_in, const int* in_sizes, int n_in,
                              void* d_out, int out_size, void* d_ws, size_t ws_size,
                              hipStream_t stream) {
    const float* x    = (const float*)d_in[0];
    const float* Wl   = (const float*)d_in[1];
    const float* bl   = (const float*)d_in[2];
    const float* Wih1 = (const float*)d_in[3];
    const float* Whh1 = (const float*)d_in[4];
    const float* bih1 = (const float*)d_in[5];
    const float* bhh1 = (const float*)d_in[6];
    const float* Wih2 = (const float*)d_in[7];
    const float* Whh2 = (const float*)d_in[8];
    const float* bih2 = (const float*)d_in[9];
    const float* bhh2 = (const float*)d_in[10];
    const float* Wa   = (const float*)d_in[11];
    const float* ba   = (const float*)d_in[12];
    float* out = (float*)d_out;

    rnn_kernel<<<NBATCH, 64, 0, stream>>>(x, Wl, bl, Wih1, Whh1, bih1, bhh1,
                                          Wih2, Whh2, bih2, bhh2, Wa, ba, out);
}

// Round 7
// 956.154 us; speedup vs baseline: 1.1312x; 1.1312x over previous
//
#include <hip/hip_runtime.h>

#define T_STEPS 2000
#define NBATCH  256
#define HID     51
#define FEAT    49
#define ROWF4   784                         // float4 per 64-step chunk (64*49/4)
#define XTOT4   (NBATCH * T_STEPS * FEAT / 4)
#define XBUFB   12544                       // bytes per staged chunk (784 * 16)
#define PSTRIDE 5                           // preact tile row stride (dwords), odd => conflict-free

typedef _Float16 v2h __attribute__((ext_vector_type(2)));

__device__ __forceinline__ float rl(float v, int lane) {
    return __int_as_float(__builtin_amdgcn_readlane(__float_as_int(v), lane));
}
__device__ __forceinline__ int rli(int v, int lane) {
    return __builtin_amdgcn_readlane(v, lane);
}
__device__ __forceinline__ float sigmoidf_fast(float x) {
    return __builtin_amdgcn_rcpf(1.0f + __builtin_amdgcn_exp2f(-1.4426950408889634f * x));
}
__device__ __forceinline__ float tanhf_fast(float x) {
    return 1.0f - 2.0f * __builtin_amdgcn_rcpf(1.0f + __builtin_amdgcn_exp2f(2.8853900817779268f * x));
}
__device__ __forceinline__ int packh2(float lo, float hi) {
    v2h p = (v2h){(_Float16)lo, (_Float16)hi};
    return __builtin_bit_cast(int, p);
}
__device__ __forceinline__ float dot2(int w, int h, float acc) {
    return __builtin_amdgcn_fdot2(__builtin_bit_cast(v2h, w),
                                  __builtin_bit_cast(v2h, h), acc, false);
}
// async global->LDS, 16B per lane: LDS dest = wave-uniform base + lane*16,
// global src = per-lane address. Tracked by vmcnt (per-wave).
__device__ __forceinline__ void gl_lds16(const void* g, void* l) {
    __builtin_amdgcn_global_load_lds(
        (const __attribute__((address_space(1))) unsigned int*)g,
        (__attribute__((address_space(3))) unsigned int*)l, 16, 0, 0);
}
// LDS-only barrier: skips the vmcnt(0)/expcnt(0) drain __syncthreads emits.
__device__ __forceinline__ void bar_lds() {
    asm volatile("s_waitcnt lgkmcnt(0)" ::: "memory");
    __builtin_amdgcn_s_barrier();
    asm volatile("" ::: "memory");
}
__device__ __forceinline__ float row_dot(const float* row, const float* __restrict__ Wl) {
    float a0 = 0, a1 = 0, a2 = 0, a3 = 0, a4 = 0, a5 = 0, a6 = 0;
#pragma unroll
    for (int j = 0; j < FEAT; j += 7) {
        a0 = fmaf(row[j    ], Wl[j    ], a0);
        a1 = fmaf(row[j + 1], Wl[j + 1], a1);
        a2 = fmaf(row[j + 2], Wl[j + 2], a2);
        a3 = fmaf(row[j + 3], Wl[j + 3], a3);
        a4 = fmaf(row[j + 4], Wl[j + 4], a4);
        a5 = fmaf(row[j + 5], Wl[j + 5], a5);
        a6 = fmaf(row[j + 6], Wl[j + 6], a6);
    }
    return ((a0 + a1) + (a2 + a3)) + ((a4 + a5) + a6);
}

#define REP26(F) F(0) F(1) F(2) F(3) F(4) F(5) F(6) F(7) F(8) F(9) F(10) F(11) F(12) \
                 F(13) F(14) F(15) F(16) F(17) F(18) F(19) F(20) F(21) F(22) F(23) F(24) F(25)

// 4 waves per sample (one per gate) — the round-0 structure (session best,
// 767 us), re-anchored. Model from rounds 0-6: single-wave VALU issue is
// ~4 cy/instr, so per-step time ~ 4*I_wave + 240*(LDS exchanges) + base.
// 4-wave gate split minimizes I (26 dots + 26 bcast + ~30 misc) at E=1.
// Only change vs round 0: x staging via global_load_lds double-buffer
// (proven rounds 3-6) instead of float4 PF/COMMIT — frees 16 VGPRs and
// ~26 instrs per chunk-boundary step. Numerics bit-identical to round 0.
__global__ __attribute__((amdgpu_flat_work_group_size(256, 256), amdgpu_waves_per_eu(1)))
void rnn_kernel(
    const float* __restrict__ x,
    const float* __restrict__ Wl, const float* __restrict__ bl,
    const float* __restrict__ Wih1, const float* __restrict__ Whh1,
    const float* __restrict__ bih1, const float* __restrict__ bhh1,
    const float* __restrict__ Wih2, const float* __restrict__ Whh2,
    const float* __restrict__ bih2, const float* __restrict__ bhh2,
    const float* __restrict__ Wa, const float* __restrict__ ba,
    float* __restrict__ out)
{
    const int n    = blockIdx.x;
    const int tid  = threadIdx.x;
    const int wid  = tid >> 6;      // gate index
    const int lane = tid & 63;
    float* optr = out + (size_t)n * T_STEPS;
    const float4* x4 = (const float4*)x;
    const int sbase = n * (T_STEPS * FEAT / 4);

    __shared__ __align__(16) char xls[2 * XBUFB];   // double-buffered x-tile
    __shared__ float pt[2][64 * PSTRIDE];           // activated-gate exchange
    __shared__ float ob[64];                        // output buffer
    
    // ---- weights: 26 packed f16 pairs per lane (named scalars) ----
#define DECLW(j) int w_##j; int sh_##j;
    REP26(DECLW)
    {
        const float* srow;
        float msk;
        if (lane < HID) { srow = Whh1 + (wid * HID + lane) * HID; msk = 1.0f; }
        else            { srow = Wih2 + wid * HID; msk = (lane == HID) ? 1.0f : 0.0f; }
        const float wh2 = Whh2[wid] * ((lane == HID) ? 1.0f : 0.0f);
#define LOADW(j) { \
        float lo = srow[2*(j)] * msk; \
        float hi = (2*(j)+1 < HID) ? srow[2*(j)+1] * msk : wh2; \
        w_##j = packh2(lo, hi); \
        asm("" : "+v"(w_##j)); }
        REP26(LOADW)
    }

    float wx = 0.0f, b = 0.0f;
    if (lane < HID) {
        wx = Wih1[wid * HID + lane];
        b  = bih1[wid * HID + lane] + bhh1[wid * HID + lane];
    } else if (lane == HID) {
        b  = bih2[wid] + bhh2[wid];
    }
    const float wav = Wa[0], bav = ba[0];
    const float bl0 = bl[0];

#define INITS(j) sh_##j = 0;
    REP26(INITS)

    float c = 0.0f, h = 0.0f;

    // ---- x staging: 784 float4 per chunk via global_load_lds (0 VGPRs) ----
    // Round i (i=0..2): wave w stages dest i*4096 + w*1024, src i*256 + tid.
    // Partial: wave0 lanes 0-15 stage the last 256 B. Linear layout matches
    // row-major xt tile (row l = floats [l*49, l*49+49)).
#define STAGE(cbase, buf) { \
    _Pragma("unroll") \
    for (int i_ = 0; i_ < 3; ++i_) { \
        int g_ = (cbase) + i_ * 256 + tid; g_ = g_ < XTOT4 ? g_ : (XTOT4 - 1); \
        gl_lds16(x4 + g_, xls + (buf) * XBUFB + i_ * 4096 + wid * 1024); \
    } \
    if (tid < 16) { \
        int g_ = (cbase) + 768 + tid; g_ = g_ < XTOT4 ? g_ : (XTOT4 - 1); \
        gl_lds16(x4 + g_, xls + (buf) * XBUFB + 12288); } }
#define VMWAIT asm volatile("s_waitcnt vmcnt(0)" ::: "memory");
#define ROWDOT(dst, buf) { \
    const float* row_ = (const float*)(xls + (buf) * XBUFB) + lane * FEAT; \
    float d_ = row_dot(row_, Wl); dst = fmaxf(d_ + bl0, 0.0f); }

    float xa, xb;
    STAGE(sbase, 0)                       // chunk 0 -> buf0
    STAGE(sbase + ROWF4, 1)               // chunk 1 -> buf1
    VMWAIT
    __builtin_amdgcn_s_barrier();         // all waves' DMAs complete
    ROWDOT(xa, 0)
    ROWDOT(xb, 1)
    STAGE(sbase + 2 * ROWF4, 0)           // chunk 2 -> buf0 (chunk 0 consumed)

    const int prow = lane * PSTRIDE;

#pragma unroll 1
    for (int t = 0; t <= T_STEPS; ++t) {
        if ((t & 63) == 0 && t > 0 && t < T_STEPS) {
            const int k = t >> 6;
            if (wid == 0) {                       // flush outputs (wave0-internal)
                int oi = 64 * (k - 1) - 1 + lane;
                float ov = ob[lane];
                if (oi >= 0) optr[oi] = ov;
            }
            xa = xb;
            VMWAIT                                // own chunk k+1 DMA done
            __builtin_amdgcn_s_barrier();         // all waves' DMAs done
            ROWDOT(xb, (k + 1) & 1)               // precompute chunk k+1
            STAGE(sbase + (k + 2) * ROWF4, k & 1) // chunk k+2 in flight
        }
        float xt = rl(xa, t & 63);

        // ---- this wave's gate preact: 2 interleaved dot2 chains ----
        float aA = fmaf(wx, xt, b), aB = 0.0f;
#define DOT(j) { if ((j) & 1) aB = dot2(w_##j, sh_##j, aB); \
                 else         aA = dot2(w_##j, sh_##j, aA); }
        REP26(DOT)
        float a = aA + aB;

        // ---- own-gate activation BEFORE exchange (wave-uniform branch) ----
        float act = (wid == 2) ? tanhf_fast(a) : sigmoidf_fast(a);

        // ---- exchange activated gates: write own, barrier, read all 4 ----
        float* ptw = pt[t & 1];
        ptw[prow + wid] = act;
        bar_lds();
        float ig = ptw[prow + 0];
        float fg = ptw[prow + 1];
        float gg = ptw[prow + 2];
        float og = ptw[prow + 3];

        // ---- short state update (redundant per wave; lane51 = LSTM2) ----
        c = fmaf(fg, c, ig * gg);
        h = og * tanhf_fast(c);
        if (t == 0 && lane >= HID) { c = 0.0f; h = 0.0f; }   // LSTM2 zero init (skew)

        if (wid == 0 && lane == HID && t > 0)                 // buffer output in LDS
            ob[t & 63] = fmaf(h, wav, bav);

        // ---- h broadcast: f16 cvt + quad_perm neighbor + 26 readlanes ----
        int hz = (int)(unsigned)__builtin_bit_cast(unsigned short, (_Float16)h);
        int nb = __builtin_amdgcn_mov_dpp(hz, 0xB1, 0xF, 0xF, true);  // lane r <-> r^1
        int pair = hz | (nb << 16);          // even lane r: h[r] | h[r+1]<<16
#define BCAST(j) sh_##j = rli(pair, 2 * (j));
        REP26(BCAST)
    }

    // final output flush: out idx 1983..1999 live in slots 0..16
    if (wid == 0 && lane <= 16) optr[1983 + lane] = ob[lane];
}

extern "C" void kernel_launch(void* const* d_in, const int* in_sizes, int n_in,
                              void* d_out, int out_size, void* d_ws, size_t ws_size,
                              hipStream_t stream) {
    const float* x    = (const float*)d_in[0];
    const float* Wl   = (const float*)d_in[1];
    const float* bl   = (const float*)d_in[2];
    const float* Wih1 = (const float*)d_in[3];
    const float* Whh1 = (const float*)d_in[4];
    const float* bih1 = (const float*)d_in[5];
    const float* bhh1 = (const float*)d_in[6];
    const float* Wih2 = (const float*)d_in[7];
    const float* Whh2 = (const float*)d_in[8];
    const float* bih2 = (const float*)d_in[9];
    const float* bhh2 = (const float*)d_in[10];
    const float* Wa   = (const float*)d_in[11];
    const float* ba   = (const float*)d_in[12];
    float* out = (float*)d_out;

    rnn_kernel<<<NBATCH, 256, 0, stream>>>(x, Wl, bl, Wih1, Whh1, bih1, bhh1,
                                           Wih2, Whh2, bih2, bhh2, Wa, ba, out);
}

// Round 8
// 915.962 us; speedup vs baseline: 1.1808x; 1.0439x over previous
//
#include <hip/hip_runtime.h>

#define T_STEPS 2000
#define NBATCH  256
#define HID     51
#define FEAT    49
#define ROWF4   784                         // 64 rows * 49 floats / 4
#define XTOT4   (NBATCH * T_STEPS * FEAT / 4)
#define PSTRIDE 5                           // preact tile row stride (dwords), odd => conflict-free

typedef _Float16 v2h __attribute__((ext_vector_type(2)));

__device__ __forceinline__ float rl(float v, int lane) {
    return __int_as_float(__builtin_amdgcn_readlane(__float_as_int(v), lane));
}
__device__ __forceinline__ int rli(int v, int lane) {
    return __builtin_amdgcn_readlane(v, lane);
}
__device__ __forceinline__ float sigmoidf_fast(float x) {
    return __builtin_amdgcn_rcpf(1.0f + __builtin_amdgcn_exp2f(-1.4426950408889634f * x));
}
__device__ __forceinline__ float tanhf_fast(float x) {
    return 1.0f - 2.0f * __builtin_amdgcn_rcpf(1.0f + __builtin_amdgcn_exp2f(2.8853900817779268f * x));
}
__device__ __forceinline__ int packh2(float lo, float hi) {
    v2h p = (v2h){(_Float16)lo, (_Float16)hi};
    return __builtin_bit_cast(int, p);
}
__device__ __forceinline__ float dot2(int w, int h, float acc) {
    return __builtin_amdgcn_fdot2(__builtin_bit_cast(v2h, w),
                                  __builtin_bit_cast(v2h, h), acc, false);
}
// LDS-only barrier: skips the vmcnt(0)/expcnt(0) drain __syncthreads emits.
__device__ __forceinline__ void bar_lds() {
    asm volatile("s_waitcnt lgkmcnt(0)" ::: "memory");
    __builtin_amdgcn_s_barrier();
    asm volatile("" ::: "memory");
}
__device__ __forceinline__ float row_dot(const float* row, const float* __restrict__ Wl) {
    float a0 = 0, a1 = 0, a2 = 0, a3 = 0, a4 = 0, a5 = 0, a6 = 0;
#pragma unroll
    for (int j = 0; j < FEAT; j += 7) {
        a0 = fmaf(row[j    ], Wl[j    ], a0);
        a1 = fmaf(row[j + 1], Wl[j + 1], a1);
        a2 = fmaf(row[j + 2], Wl[j + 2], a2);
        a3 = fmaf(row[j + 3], Wl[j + 3], a3);
        a4 = fmaf(row[j + 4], Wl[j + 4], a4);
        a5 = fmaf(row[j + 5], Wl[j + 5], a5);
        a6 = fmaf(row[j + 6], Wl[j + 6], a6);
    }
    return ((a0 + a1) + (a2 + a3)) + ((a4 + a5) + a6);
}

#define REP26(F) F(0) F(1) F(2) F(3) F(4) F(5) F(6) F(7) F(8) F(9) F(10) F(11) F(12) \
                 F(13) F(14) F(15) F(16) F(17) F(18) F(19) F(20) F(21) F(22) F(23) F(24) F(25)

// 4 waves per sample (one per gate) — round-0 structure verbatim (session
// best, 767 us rocprof). Session model (R0-R7): step ~= 4*I_wave +
// 240*(LDS exchanges) + serial tail. R7 proved DMA staging pollutes the
// exchange path (+90 cy/step); register PF/COMMIT staging restored.
// ONLY change vs round 0: gate dot2 accumulation split 2 -> 4 chains.
// If fdot2 dep latency > 8 cy the 13-deep chains were latency-bound
// (13*L on the pre-exchange path); 4 chains halve that. If issue-bound,
// the change is free (same 26 issues).
__global__ __attribute__((amdgpu_flat_work_group_size(256, 256), amdgpu_waves_per_eu(1)))
void rnn_kernel(
    const float* __restrict__ x,
    const float* __restrict__ Wl, const float* __restrict__ bl,
    const float* __restrict__ Wih1, const float* __restrict__ Whh1,
    const float* __restrict__ bih1, const float* __restrict__ bhh1,
    const float* __restrict__ Wih2, const float* __restrict__ Whh2,
    const float* __restrict__ bih2, const float* __restrict__ bhh2,
    const float* __restrict__ Wa, const float* __restrict__ ba,
    float* __restrict__ out)
{
    const int n    = blockIdx.x;
    const int tid  = threadIdx.x;
    const int wid  = tid >> 6;      // gate index
    const int lane = tid & 63;
    float* optr = out + (size_t)n * T_STEPS;
    const float4* x4 = (const float4*)x;
    const int sbase = n * (T_STEPS * FEAT / 4);

    __shared__ float xt_[64 * FEAT];            // 12544 B x-tile
    __shared__ float pt[2][64 * PSTRIDE];       // 2560 B activated-gate exchange
    __shared__ float ob[64];                    // 256 B output buffer
    float4* t4 = (float4*)xt_;

    // ---- weights: 26 packed f16 pairs per lane (named scalars) ----
#define DECLW(j) int w_##j; int sh_##j;
    REP26(DECLW)
    {
        const float* srow;
        float msk;
        if (lane < HID) { srow = Whh1 + (wid * HID + lane) * HID; msk = 1.0f; }
        else            { srow = Wih2 + wid * HID; msk = (lane == HID) ? 1.0f : 0.0f; }
        const float wh2 = Whh2[wid] * ((lane == HID) ? 1.0f : 0.0f);
#define LOADW(j) { \
        float lo = srow[2*(j)] * msk; \
        float hi = (2*(j)+1 < HID) ? srow[2*(j)+1] * msk : wh2; \
        w_##j = packh2(lo, hi); \
        asm("" : "+v"(w_##j)); }
        REP26(LOADW)
    }

    float wx = 0.0f, b = 0.0f;
    if (lane < HID) {
        wx = Wih1[wid * HID + lane];
        b  = bih1[wid * HID + lane] + bhh1[wid * HID + lane];
    } else if (lane == HID) {
        b  = bih2[wid] + bhh2[wid];
    }
    const float wav = Wa[0], bav = ba[0];
    const float bl0 = bl[0];

#define INITS(j) sh_##j = 0;
    REP26(INITS)

    float c = 0.0f, h = 0.0f;

    // ---- x prefetch: 784 float4 per 64-step chunk spread over 256 threads ----
    float4 p0, p1, p2, p3;
#define PF(base) { \
        int g0_ = (base) + tid;       g0_ = g0_ < XTOT4 ? g0_ : (XTOT4 - 1); p0 = x4[g0_]; \
        int g1_ = (base) + 256 + tid; g1_ = g1_ < XTOT4 ? g1_ : (XTOT4 - 1); p1 = x4[g1_]; \
        int g2_ = (base) + 512 + tid; g2_ = g2_ < XTOT4 ? g2_ : (XTOT4 - 1); p2 = x4[g2_]; \
        if (tid < 16) { int g3_ = (base) + 768 + tid; g3_ = g3_ < XTOT4 ? g3_ : (XTOT4 - 1); p3 = x4[g3_]; } }
#define COMMIT { t4[tid] = p0; t4[tid + 256] = p1; t4[tid + 512] = p2; \
                 if (tid < 16) t4[tid + 768] = p3; }
#define ROWDOT(dst) { float d_ = row_dot(&xt_[lane * FEAT], Wl); \
                      dst = fmaxf(d_ + bl0, 0.0f); }

    float xa, xb;
    PF(sbase)              COMMIT  bar_lds();  ROWDOT(xa)                // chunk 0
    PF(sbase + ROWF4)      bar_lds();  COMMIT  bar_lds();  ROWDOT(xb)    // chunk 1
    PF(sbase + 2 * ROWF4)                                                // chunk 2 in flight

    const int prow = lane * PSTRIDE;

#pragma unroll 1
    for (int t = 0; t <= T_STEPS; ++t) {
        if ((t & 63) == 0 && t > 0 && t < T_STEPS) {
            const int k = t >> 6;
            if (wid == 0) {                       // flush outputs (wave0-internal)
                int oi = 64 * (k - 1) - 1 + lane;
                float ov = ob[lane];
                if (oi >= 0) optr[oi] = ov;
            }
            xa = xb;
            COMMIT                                 // chunk k+1 -> x-tile
            bar_lds();
            ROWDOT(xb)
            PF(sbase + (k + 2) * ROWF4)            // chunk k+2 in flight
        }
        float xt = rl(xa, t & 63);

        // ---- this wave's gate preact: 4 interleaved dot2 chains ----
        float aA = fmaf(wx, xt, b), aB = 0.0f, aC = 0.0f, aD = 0.0f;
#define DOT(j) { if      (((j) & 3) == 0) aA = dot2(w_##j, sh_##j, aA); \
                 else if (((j) & 3) == 1) aB = dot2(w_##j, sh_##j, aB); \
                 else if (((j) & 3) == 2) aC = dot2(w_##j, sh_##j, aC); \
                 else                     aD = dot2(w_##j, sh_##j, aD); }
        REP26(DOT)
        float a = (aA + aB) + (aC + aD);

        // ---- own-gate activation BEFORE exchange (wave-uniform branch) ----
        float act = (wid == 2) ? tanhf_fast(a) : sigmoidf_fast(a);

        // ---- exchange activated gates: write own, barrier, read all 4 ----
        float* ptw = pt[t & 1];
        ptw[prow + wid] = act;
        bar_lds();
        float ig = ptw[prow + 0];
        float fg = ptw[prow + 1];
        float gg = ptw[prow + 2];
        float og = ptw[prow + 3];

        // ---- short state update (redundant per wave; lane51 = LSTM2) ----
        c = fmaf(fg, c, ig * gg);
        h = og * tanhf_fast(c);
        if (t == 0 && lane >= HID) { c = 0.0f; h = 0.0f; }   // LSTM2 zero init (skew)

        if (wid == 0 && lane == HID && t > 0)                 // buffer output in LDS
            ob[t & 63] = fmaf(h, wav, bav);

        // ---- h broadcast: f16 cvt + quad_perm neighbor + 26 readlanes ----
        int hz = (int)(unsigned)__builtin_bit_cast(unsigned short, (_Float16)h);
        int nb = __builtin_amdgcn_mov_dpp(hz, 0xB1, 0xF, 0xF, true);  // lane r <-> r^1
        int pair = hz | (nb << 16);          // even lane r: h[r] | h[r+1]<<16
#define BCAST(j) sh_##j = rli(pair, 2 * (j));
        REP26(BCAST)
    }

    // final output flush: out idx 1983..1999 live in slots 0..16
    if (wid == 0 && lane <= 16) optr[1983 + lane] = ob[lane];
}

extern "C" void kernel_launch(void* const* d_in, const int* in_sizes, int n_in,
                              void* d_out, int out_size, void* d_ws, size_t ws_size,
                              hipStream_t stream) {
    const float* x    = (const float*)d_in[0];
    const float* Wl   = (const float*)d_in[1];
    const float* bl   = (const float*)d_in[2];
    const float* Wih1 = (const float*)d_in[3];
    const float* Whh1 = (const float*)d_in[4];
    const float* bih1 = (const float*)d_in[5];
    const float* bhh1 = (const float*)d_in[6];
    const float* Wih2 = (const float*)d_in[7];
    const float* Whh2 = (const float*)d_in[8];
    const float* bih2 = (const float*)d_in[9];
    const float* bhh2 = (const float*)d_in[10];
    const float* Wa   = (const float*)d_in[11];
    const float* ba   = (const float*)d_in[12];
    float* out = (float*)d_out;

    rnn_kernel<<<NBATCH, 256, 0, stream>>>(x, Wl, bl, Wih1, Whh1, bih1, bhh1,
                                           Wih2, Whh2, bih2, bhh2, Wa, ba, out);
}